// Round 13
// baseline (86.688 us; speedup 1.0000x reference)
//
#include <hip/hip_runtime.h>

// RoiPooling (crop_and_resize, bilinear): x (1,128,128,256) f32 NHWC,
// rois (4000,4) f32 [y1,x1,y2,x2] in [0,1] -> out (4000,7,7,256) f32.
//
// R13: cell sort by (y0, x0>>4) = 1024 segments, generated at PAIR
// parallelism (28k threads x 7 keys -> cheap like R12), + LDS strip
// staging pool: each block stages rows {y0,y0+1} x 17 cols (34KB) once,
// serves all its cells' gathers from LDS (conflict-free b128). L2 read
// traffic 784MB -> ~100MB; pool becomes NT-write-bound (~30us floor).

typedef float v4f __attribute__((ext_vector_type(4)));

constexpr int H = 128, W = 128, C = 256;
constexpr int PH = 7, PW = 7;
constexpr int NROI = 4000;
constexpr int NPAIR = NROI * PH;                 // 28000
constexpr int NCELL = NROI * PH * PW;            // 196000
constexpr int NBKT = 128 * 8;                    // (y0, x0>>4) segments
constexpr int CSTRIDE = 16;                      // ints; 64B per counter
constexpr int PAIR_BLOCKS = (NPAIR + 255) / 256; // 110
constexpr int BPS = 3;                           // blocks per segment
constexpr int P2_BLOCKS = NBKT * BPS;            // 3072
constexpr size_t WS_CNT  = (size_t)NBKT * CSTRIDE;
constexpr size_t WS_INTS = 2 * WS_CNT + (NBKT + 1) + NCELL;

__global__ __launch_bounds__(256) void zero_counts(int* p) {
    const int n = (int)(2 * WS_CNT);
    const int i = blockIdx.x * 256 + threadIdx.x;
    for (int j = i; j < n; j += 32 * 256) p[j] = 0;
}

// y0 and the 7 x0s for a pair; key = (y0<<3)|(x0>>4).
__device__ __forceinline__ void pair_geom(const float* __restrict__ rois, int pr,
                                          int& y0, int* x0s)
{
    const int r  = pr / PH;
    const int iy = pr - r * PH;
    const float y1 = rois[r * 4 + 0];
    const float x1 = rois[r * 4 + 1];
    const float y2 = rois[r * 4 + 2];
    const float x2 = rois[r * 4 + 3];
    const float ys = y1 * (float)(H - 1) + (float)iy * ((y2 - y1) * (float)(H - 1) / (float)(PH - 1));
    y0 = min(max((int)floorf(ys), 0), H - 1);
#pragma unroll
    for (int ix = 0; ix < PW; ++ix) {
        const float xs = x1 * (float)(W - 1) + (float)ix * ((x2 - x1) * (float)(W - 1) / (float)(PW - 1));
        x0s[ix] = min(max((int)floorf(xs), 0), W - 1);
    }
}

__global__ __launch_bounds__(256) void hist_pairs(const float* __restrict__ rois,
                                                  int* __restrict__ cnt)
{
    __shared__ int lh[NBKT];
    for (int i = threadIdx.x; i < NBKT; i += 256) lh[i] = 0;
    __syncthreads();
    const int pr = blockIdx.x * 256 + threadIdx.x;
    if (pr < NPAIR) {
        int y0, x0s[PW];
        pair_geom(rois, pr, y0, x0s);
        const int base = y0 << 3;
#pragma unroll
        for (int ix = 0; ix < PW; ++ix)
            atomicAdd(&lh[base | (x0s[ix] >> 4)], 1);
    }
    __syncthreads();
    for (int i = threadIdx.x; i < NBKT; i += 256) {
        const int n = lh[i];
        if (n) atomicAdd(&cnt[i * CSTRIDE], n);
    }
}

__global__ __launch_bounds__(1024) void prefix_sum(const int* __restrict__ cnt,
                                                   int* __restrict__ P)
{
    __shared__ int s[NBKT];
    const int t = threadIdx.x;
    s[t] = cnt[t * CSTRIDE];
    __syncthreads();
    for (int off = 1; off < NBKT; off <<= 1) {
        const int v = (t >= off) ? s[t - off] : 0;
        __syncthreads();
        s[t] += v;
        __syncthreads();
    }
    P[t + 1] = s[t];
    if (t == 0) P[0] = 0;
}

__global__ __launch_bounds__(256) void scatter_pairs(const float* __restrict__ rois,
                                                     const int* __restrict__ P,
                                                     int* __restrict__ head,
                                                     int* __restrict__ list)
{
    __shared__ int lcnt[NBKT];
    __shared__ int gbase[NBKT];
    for (int i = threadIdx.x; i < NBKT; i += 256) lcnt[i] = 0;
    __syncthreads();
    const int pr = blockIdx.x * 256 + threadIdx.x;
    const bool active = pr < NPAIR;
    int keys[PW], ranks[PW];
    if (active) {
        int y0, x0s[PW];
        pair_geom(rois, pr, y0, x0s);
        const int base = y0 << 3;
#pragma unroll
        for (int ix = 0; ix < PW; ++ix) {
            keys[ix] = base | (x0s[ix] >> 4);
            ranks[ix] = atomicAdd(&lcnt[keys[ix]], 1);
        }
    }
    __syncthreads();
    for (int i = threadIdx.x; i < NBKT; i += 256) {
        const int n = lcnt[i];
        gbase[i] = n ? P[i] + atomicAdd(&head[i * CSTRIDE], n) : 0;
    }
    __syncthreads();
    if (active) {
#pragma unroll
        for (int ix = 0; ix < PW; ++ix)
            list[gbase[keys[ix]] + ranks[ix]] = (pr << 3) | ix;
    }
}

__global__ __launch_bounds__(256) void roi_pool_strip(
    const float* __restrict__ x, const float* __restrict__ rois,
    float* __restrict__ out, const int* __restrict__ P,
    const int* __restrict__ list)
{
    __shared__ float lds[2][17][256];            // 34KB: rows y0,y0+1 x 17 cols

    // XCD-affine mapping: XCD j owns segments [j*128,(j+1)*128) = 16 y-rows.
    const int xcd = blockIdx.x & 7;
    const int within = blockIdx.x >> 3;          // 0..383
    const int s = xcd * 128 + within / BPS;
    const int j = within - (within / BPS) * BPS; // 0..BPS-1
    const int start = P[s];
    const int n = P[s + 1] - start;
    if (n == 0) return;

    const int y0s   = s >> 3;
    const int x0base = (s & 7) << 4;
    const int wave = threadIdx.x >> 6;
    const int lane = threadIdx.x & 63;
    const int lane4 = lane * 4;

    // Stage 34 col-chunks (2 rows x 17 cols, 1KB each).
    for (int chunk = wave; chunk < 34; chunk += 4) {
        const int row = chunk < 17 ? 0 : 1;
        const int col = chunk - row * 17;
        const int gy = min(y0s + row, H - 1);
        const int gx = min(x0base + col, W - 1);
        const v4f v = *(const v4f*)(x + (unsigned)((gy << 7) + gx) * C + lane4);
        *(v4f*)(&lds[row][col][lane4]) = v;
    }
    __syncthreads();

    const int slot = j * 4 + wave;               // 0..11
    for (int t = slot; t < n; t += BPS * 4) {
        const int packed = list[start + t];
        const int pr = packed >> 3;
        const int ix = packed & 7;
        const int r  = pr / PH;
        const int iy = pr - r * PH;

        const float y1 = rois[r * 4 + 0];
        const float x1 = rois[r * 4 + 1];
        const float y2 = rois[r * 4 + 2];
        const float x2 = rois[r * 4 + 3];

        // Match reference order exactly.
        const float ys = y1 * (float)(H - 1) + (float)iy * ((y2 - y1) * (float)(H - 1) / (float)(PH - 1));
        const float xs = x1 * (float)(W - 1) + (float)ix * ((x2 - x1) * (float)(W - 1) / (float)(PW - 1));

        const float y0f = floorf(ys);
        const float x0f = floorf(xs);
        const float wy = ys - y0f;
        const float wx = xs - x0f;

        int y0  = (int)y0f; y0  = min(max(y0, 0), H - 1);   // == y0s
        int y1i = min(y0 + 1, H - 1);
        int x0  = (int)x0f; x0  = min(max(x0, 0), W - 1);
        int x1c = min(x0 + 1, W - 1);

        const bool valid = (ys >= 0.0f) & (ys <= (float)(H - 1)) &
                           (xs >= 0.0f) & (xs <= (float)(W - 1));

        const int ry1 = y1i - y0;                // 0 or 1
        const int lx0 = x0  - x0base;            // 0..15
        const int lx1 = x1c - x0base;            // 0..16

        const v4f a = *(const v4f*)(&lds[0][lx0][lane4]);
        const v4f b = *(const v4f*)(&lds[0][lx1][lane4]);
        const v4f c = *(const v4f*)(&lds[ry1][lx0][lane4]);
        const v4f d = *(const v4f*)(&lds[ry1][lx1][lane4]);

        const v4f top = a * (1.0f - wx) + b * wx;
        const v4f bot = c * (1.0f - wx) + d * wx;
        v4f res = top * (1.0f - wy) + bot * wy;
        if (!valid) res = (v4f)0.0f;
        __builtin_nontemporal_store(res, (v4f*)(out + (unsigned)(r * 49 + iy * 7 + ix) * C + lane4));
    }
}

// Fallback (ws too small): direct kernel over pairs.
__global__ __launch_bounds__(256) void roi_pool_plain(
    const float* __restrict__ x, const float* __restrict__ rois,
    float* __restrict__ out)
{
    const int wave = threadIdx.x >> 6;
    const int lane = threadIdx.x & 63;
    const int pr = blockIdx.x * 4 + wave;
    if (pr >= NPAIR) return;
    const int r  = pr / PH;
    const int iy = pr - r * PH;
    const unsigned c4 = (unsigned)lane * 4u;

    const float y1 = rois[r * 4 + 0];
    const float x1 = rois[r * 4 + 1];
    const float y2 = rois[r * 4 + 2];
    const float x2 = rois[r * 4 + 3];

    const float ys = y1 * (float)(H - 1) + (float)iy * ((y2 - y1) * (float)(H - 1) / (float)(PH - 1));
    const float y0f = floorf(ys);
    const float wy = ys - y0f;
    int y0  = (int)y0f; y0  = min(max(y0, 0), H - 1);
    int y1i = min(y0 + 1, H - 1);
    const bool vy = (ys >= 0.0f) & (ys <= (float)(H - 1));

    const float* __restrict__ row0 = x + (unsigned)y0  * (W * C);
    const float* __restrict__ row1 = x + (unsigned)y1i * (W * C);
    float* __restrict__ obase = out + (unsigned)(r * 49 + iy * 7) * C;

#pragma unroll
    for (int ix = 0; ix < PW; ++ix) {
        const float xs = x1 * (float)(W - 1) + (float)ix * ((x2 - x1) * (float)(W - 1) / (float)(PW - 1));
        const float x0f = floorf(xs);
        const float wx = xs - x0f;
        int x0  = (int)x0f; x0  = min(max(x0, 0), W - 1);
        int x1c = min(x0 + 1, W - 1);
        const bool v = vy & (xs >= 0.0f) & (xs <= (float)(W - 1));

        const v4f a = *(const v4f*)(row0 + (unsigned)x0  * C + c4);
        const v4f b = *(const v4f*)(row0 + (unsigned)x1c * C + c4);
        const v4f c = *(const v4f*)(row1 + (unsigned)x0  * C + c4);
        const v4f d = *(const v4f*)(row1 + (unsigned)x1c * C + c4);

        const v4f top = a * (1.0f - wx) + b * wx;
        const v4f bot = c * (1.0f - wx) + d * wx;
        v4f res = top * (1.0f - wy) + bot * wy;
        if (!v) res = (v4f)0.0f;
        __builtin_nontemporal_store(res, (v4f*)(obase + (unsigned)ix * C + c4));
    }
}

extern "C" void kernel_launch(void* const* d_in, const int* in_sizes, int n_in,
                              void* d_out, int out_size, void* d_ws, size_t ws_size,
                              hipStream_t stream)
{
    const float* x    = (const float*)d_in[0];
    const float* rois = (const float*)d_in[1];
    float* out = (float*)d_out;

    if (ws_size >= WS_INTS * sizeof(int)) {
        int* cnt  = (int*)d_ws;
        int* head = cnt + WS_CNT;
        int* P    = head + WS_CNT;
        int* list = P + (NBKT + 1);
        zero_counts<<<32, 256, 0, stream>>>(cnt);
        hist_pairs<<<PAIR_BLOCKS, 256, 0, stream>>>(rois, cnt);
        prefix_sum<<<1, NBKT, 0, stream>>>(cnt, P);
        scatter_pairs<<<PAIR_BLOCKS, 256, 0, stream>>>(rois, P, head, list);
        roi_pool_strip<<<P2_BLOCKS, 256, 0, stream>>>(x, rois, out, P, list);
    } else {
        roi_pool_plain<<<(NPAIR + 3) / 4, 256, 0, stream>>>(x, rois, out);
    }
}

// Round 14
// 60.938 us; speedup vs baseline: 1.4226x; 1.4226x over previous
//
#include <hip/hip_runtime.h>

// RoiPooling (crop_and_resize, bilinear): x (1,128,128,256) f32 NHWC,
// rois (4000,4) f32 [y1,x1,y2,x2] in [0,1] -> out (4000,7,7,256) f32.
//
// R14: R12 pool (best known: pair-granular, y0-sorted, flat XCD partition,
// 7 cells/wave, NT stores) + atomic-free 4-dispatch sort:
//   hist: per-block PRIVATE count vectors (written unconditionally -> no
//         zero kernel, no global atomics, no 0xAA hazard)
//   prefix: 1 block computes totals, global prefix, and per-(block,bucket)
//         exclusive bases
//   scatter: LDS-rank only, direct placement at base[blk][b]+rank
// R13's LDS staging retired: cell-granular list + 34KB LDS + static
// segment assignment cost more than the L2-read savings.

typedef float v4f __attribute__((ext_vector_type(4)));

constexpr int H = 128, W = 128, C = 256;
constexpr int PH = 7, PW = 7;
constexpr int NROI = 4000;
constexpr int NPAIR = NROI * PH;                 // 28000
constexpr int RBUCK = 128;                       // one bucket per y0 row
constexpr int PAIR_BLOCKS = (NPAIR + 255) / 256; // 110
constexpr int NXCD = 8;
constexpr int M = NPAIR / NXCD;                  // 3500 pairs per XCD
constexpr int GROUPS = 256;                      // blocks per XCD
constexpr int P2_BLOCKS = NXCD * GROUPS;         // 2048
// ws: blockcnt[110][128] | base[110][128] | list[28000]
constexpr size_t WS_INTS = (size_t)PAIR_BLOCKS * RBUCK * 2 + NPAIR;

__device__ __forceinline__ int pair_ybucket(const float* __restrict__ rois, int pr) {
    const int r  = pr / PH;
    const int iy = pr - r * PH;
    const float y1 = rois[r * 4 + 0];
    const float y2 = rois[r * 4 + 2];
    const float ys = y1 * (float)(H - 1) + (float)iy * ((y2 - y1) * (float)(H - 1) / (float)(PH - 1));
    int y0 = (int)floorf(ys);
    return min(max(y0, 0), H - 1);
}

__global__ __launch_bounds__(256) void hist_pairs(const float* __restrict__ rois,
                                                  int* __restrict__ blockcnt)
{
    __shared__ int lh[RBUCK];
    if (threadIdx.x < RBUCK) lh[threadIdx.x] = 0;
    __syncthreads();
    const int pr = blockIdx.x * 256 + threadIdx.x;
    if (pr < NPAIR) atomicAdd(&lh[pair_ybucket(rois, pr)], 1);
    __syncthreads();
    if (threadIdx.x < RBUCK)
        blockcnt[blockIdx.x * RBUCK + threadIdx.x] = lh[threadIdx.x];
}

__global__ __launch_bounds__(128) void prefix_base(const int* __restrict__ blockcnt,
                                                   int* __restrict__ base)
{
    __shared__ int s[RBUCK];
    const int t = threadIdx.x;
    int tot = 0;
    for (int blk = 0; blk < PAIR_BLOCKS; ++blk) tot += blockcnt[blk * RBUCK + t];
    s[t] = tot;
    __syncthreads();
    for (int off = 1; off < RBUCK; off <<= 1) {
        const int v = (t >= off) ? s[t - off] : 0;
        __syncthreads();
        s[t] += v;
        __syncthreads();
    }
    int run = (t == 0) ? 0 : s[t - 1];           // exclusive global prefix
    for (int blk = 0; blk < PAIR_BLOCKS; ++blk) {
        const int v = blockcnt[blk * RBUCK + t];
        base[blk * RBUCK + t] = run;
        run += v;
    }
}

__global__ __launch_bounds__(256) void scatter_pairs(const float* __restrict__ rois,
                                                     const int* __restrict__ base,
                                                     int* __restrict__ list)
{
    __shared__ int lcnt[RBUCK];
    __shared__ int gbase[RBUCK];
    if (threadIdx.x < RBUCK) {
        lcnt[threadIdx.x] = 0;
        gbase[threadIdx.x] = base[blockIdx.x * RBUCK + threadIdx.x];
    }
    __syncthreads();
    const int pr = blockIdx.x * 256 + threadIdx.x;
    if (pr < NPAIR) {
        const int b = pair_ybucket(rois, pr);
        const int rank = atomicAdd(&lcnt[b], 1);
        const int r  = pr / PH;
        const int iy = pr - r * PH;
        list[gbase[b] + rank] = (r << 3) | iy;   // packed
    }
}

__global__ __launch_bounds__(256) void roi_pool_pairs(
    const float* __restrict__ x, const float* __restrict__ rois,
    float* __restrict__ out, const int* __restrict__ list)
{
    const int xcd = blockIdx.x & (NXCD - 1);   // heuristic: == XCD id
    const int grp = blockIdx.x >> 3;
    const int wave = threadIdx.x >> 6;
    const int lane = threadIdx.x & 63;
    const unsigned c4 = (unsigned)lane * 4u;
    const int base = xcd * M;

    for (int i = grp * 4 + wave; i < M; i += GROUPS * 4) {
        const int packed = list[base + i];
        const int r  = packed >> 3;
        const int iy = packed & 7;

        const float y1 = rois[r * 4 + 0];
        const float x1 = rois[r * 4 + 1];
        const float y2 = rois[r * 4 + 2];
        const float x2 = rois[r * 4 + 3];

        // Match reference order exactly.
        const float ys = y1 * (float)(H - 1) + (float)iy * ((y2 - y1) * (float)(H - 1) / (float)(PH - 1));
        const float y0f = floorf(ys);
        const float wy = ys - y0f;
        int y0  = (int)y0f; y0  = min(max(y0, 0), H - 1);
        int y1i = min(y0 + 1, H - 1);
        const bool vy = (ys >= 0.0f) & (ys <= (float)(H - 1));

        const float* __restrict__ row0 = x + (unsigned)y0  * (W * C);
        const float* __restrict__ row1 = x + (unsigned)y1i * (W * C);
        float* __restrict__ obase = out + (unsigned)(r * 49 + iy * 7) * C;

#pragma unroll
        for (int ix = 0; ix < PW; ++ix) {
            const float xs = x1 * (float)(W - 1) + (float)ix * ((x2 - x1) * (float)(W - 1) / (float)(PW - 1));
            const float x0f = floorf(xs);
            const float wx = xs - x0f;
            int x0  = (int)x0f; x0  = min(max(x0, 0), W - 1);
            int x1c = min(x0 + 1, W - 1);
            const bool v = vy & (xs >= 0.0f) & (xs <= (float)(W - 1));

            const v4f a = *(const v4f*)(row0 + (unsigned)x0  * C + c4);
            const v4f b = *(const v4f*)(row0 + (unsigned)x1c * C + c4);
            const v4f c = *(const v4f*)(row1 + (unsigned)x0  * C + c4);
            const v4f d = *(const v4f*)(row1 + (unsigned)x1c * C + c4);

            const v4f top = a * (1.0f - wx) + b * wx;
            const v4f bot = c * (1.0f - wx) + d * wx;
            v4f res = top * (1.0f - wy) + bot * wy;
            if (!v) res = (v4f)0.0f;
            __builtin_nontemporal_store(res, (v4f*)(obase + (unsigned)ix * C + c4));
        }
    }
}

// Fallback (ws too small): direct kernel over pairs.
__global__ __launch_bounds__(256) void roi_pool_plain(
    const float* __restrict__ x, const float* __restrict__ rois,
    float* __restrict__ out)
{
    const int wave = threadIdx.x >> 6;
    const int lane = threadIdx.x & 63;
    const int pr = blockIdx.x * 4 + wave;
    if (pr >= NPAIR) return;
    const int r  = pr / PH;
    const int iy = pr - r * PH;
    const unsigned c4 = (unsigned)lane * 4u;

    const float y1 = rois[r * 4 + 0];
    const float x1 = rois[r * 4 + 1];
    const float y2 = rois[r * 4 + 2];
    const float x2 = rois[r * 4 + 3];

    const float ys = y1 * (float)(H - 1) + (float)iy * ((y2 - y1) * (float)(H - 1) / (float)(PH - 1));
    const float y0f = floorf(ys);
    const float wy = ys - y0f;
    int y0  = (int)y0f; y0  = min(max(y0, 0), H - 1);
    int y1i = min(y0 + 1, H - 1);
    const bool vy = (ys >= 0.0f) & (ys <= (float)(H - 1));

    const float* __restrict__ row0 = x + (unsigned)y0  * (W * C);
    const float* __restrict__ row1 = x + (unsigned)y1i * (W * C);
    float* __restrict__ obase = out + (unsigned)(r * 49 + iy * 7) * C;

#pragma unroll
    for (int ix = 0; ix < PW; ++ix) {
        const float xs = x1 * (float)(W - 1) + (float)ix * ((x2 - x1) * (float)(W - 1) / (float)(PW - 1));
        const float x0f = floorf(xs);
        const float wx = xs - x0f;
        int x0  = (int)x0f; x0  = min(max(x0, 0), W - 1);
        int x1c = min(x0 + 1, W - 1);
        const bool v = vy & (xs >= 0.0f) & (xs <= (float)(W - 1));

        const v4f a = *(const v4f*)(row0 + (unsigned)x0  * C + c4);
        const v4f b = *(const v4f*)(row0 + (unsigned)x1c * C + c4);
        const v4f c = *(const v4f*)(row1 + (unsigned)x0  * C + c4);
        const v4f d = *(const v4f*)(row1 + (unsigned)x1c * C + c4);

        const v4f top = a * (1.0f - wx) + b * wx;
        const v4f bot = c * (1.0f - wx) + d * wx;
        v4f res = top * (1.0f - wy) + bot * wy;
        if (!v) res = (v4f)0.0f;
        __builtin_nontemporal_store(res, (v4f*)(obase + (unsigned)ix * C + c4));
    }
}

extern "C" void kernel_launch(void* const* d_in, const int* in_sizes, int n_in,
                              void* d_out, int out_size, void* d_ws, size_t ws_size,
                              hipStream_t stream)
{
    const float* x    = (const float*)d_in[0];
    const float* rois = (const float*)d_in[1];
    float* out = (float*)d_out;

    if (ws_size >= WS_INTS * sizeof(int)) {
        int* blockcnt = (int*)d_ws;
        int* base     = blockcnt + (size_t)PAIR_BLOCKS * RBUCK;
        int* list     = base + (size_t)PAIR_BLOCKS * RBUCK;
        hist_pairs<<<PAIR_BLOCKS, 256, 0, stream>>>(rois, blockcnt);
        prefix_base<<<1, 128, 0, stream>>>(blockcnt, base);
        scatter_pairs<<<PAIR_BLOCKS, 256, 0, stream>>>(rois, base, list);
        roi_pool_pairs<<<P2_BLOCKS, 256, 0, stream>>>(x, rois, out, list);
    } else {
        roi_pool_plain<<<(NPAIR + 3) / 4, 256, 0, stream>>>(x, rois, out);
    }
}